// Round 1
// baseline (208.569 us; speedup 1.0000x reference)
//
#include <hip/hip_runtime.h>
#include <hip/hip_bf16.h>
#include <stdint.h>
#include <math.h>

// Problem constants (fixed by setup_inputs)
#define BATCH 8192   // B rows of embeddings
#define DIM   2048   // D feature dim
#define KDIR  512    // K directions
#define NPTS  17     // quadrature points

typedef _Float16 half8  __attribute__((ext_vector_type(8)));
typedef float   floatx4 __attribute__((ext_vector_type(4)));

#define AS1 __attribute__((address_space(1)))
#define AS3 __attribute__((address_space(3)))

// async global->LDS, 16B per lane. LDS dest must be wave-uniform base + lane*16.
__device__ __forceinline__ void g2l16(const void* g, void* l) {
    __builtin_amdgcn_global_load_lds((AS1 void*)(uintptr_t)g, (AS3 void*)l, 16u, 0, 0u);
}

// ---------------------------------------------------------------------------
// K1: column sum-of-squares of directions -> inv_norm[k] = 1/max(||d_k||,1e-12)
// one wave per column
__global__ __launch_bounds__(64) void col_norms(const float* __restrict__ dir,
                                                float* __restrict__ invn) {
    const int k = blockIdx.x;
    const int lane = threadIdx.x;
    float s = 0.f;
    for (int r = lane; r < DIM; r += 64) {
        float v = dir[(size_t)r * KDIR + k];
        s = fmaf(v, v, s);
    }
    for (int off = 32; off > 0; off >>= 1) s += __shfl_down(s, off, 64);
    if (lane == 0) invn[k] = 1.0f / fmaxf(sqrtf(s), 1e-12f);
}

// ---------------------------------------------------------------------------
// K2: dT[n][kdim] = fp16( dir[kdim][n] * invn[n] )  -- 64x64 LDS tile transpose
__global__ __launch_bounds__(256) void make_dT(const float* __restrict__ dir,
                                               const float* __restrict__ invn,
                                               _Float16* __restrict__ dT) {
    __shared__ float tile[64][65];
    const int i0 = blockIdx.x * 64;   // DIM
    const int k0 = blockIdx.y * 64;   // KDIR
    const int tid = threadIdx.x;
    #pragma unroll
    for (int it = 0; it < 16; ++it) {
        int idx = tid + it * 256;
        int r = idx >> 6, c = idx & 63;
        tile[c][r] = dir[(size_t)(i0 + r) * KDIR + (k0 + c)] * invn[k0 + c];
    }
    __syncthreads();
    #pragma unroll
    for (int it = 0; it < 16; ++it) {
        int idx = tid + it * 256;
        int c = idx >> 6, i = idx & 63;
        dT[(size_t)(k0 + c) * DIM + (i0 + i)] = (_Float16)tile[c][i];
    }
}

// ---------------------------------------------------------------------------
// K3: embeddings fp32 -> fp16 (8 elems/thread, 32B loads -> 16B store)
__global__ __launch_bounds__(256) void cvt_f16(const float* __restrict__ x,
                                               _Float16* __restrict__ y) {
    const size_t i = ((size_t)blockIdx.x * 256 + threadIdx.x) * 8;
    floatx4 a = *(const floatx4*)(x + i);
    floatx4 b = *(const floatx4*)(x + i + 4);
    half8 h;
    h[0] = (_Float16)a[0]; h[1] = (_Float16)a[1];
    h[2] = (_Float16)a[2]; h[3] = (_Float16)a[3];
    h[4] = (_Float16)b[0]; h[5] = (_Float16)b[1];
    h[6] = (_Float16)b[2]; h[7] = (_Float16)b[3];
    *(half8*)(y + i) = h;
}

// ---------------------------------------------------------------------------
// K4: fp16 MFMA GEMM, m97 structure: 128x128 tile, BK=32, global_load_lds 16B.
// A[m][k] row-major (BATCH x DIM), Bt[n][k] row-major (KDIR x DIM), C fp32.
// 4 waves in 2x2 grid, each wave 64x64 = 4x4 frags of 16x16x32.
__global__ __launch_bounds__(256) void gemm16(const _Float16* __restrict__ A,
                                              const _Float16* __restrict__ Bt,
                                              float* __restrict__ C) {
    __shared__ _Float16 sA[128 * 32];   // [m][k], 64B rows -> conflict-free b128 reads
    __shared__ _Float16 sB[128 * 32];

    const int tid  = threadIdx.x;
    const int lane = tid & 63;
    const int wave = tid >> 6;
    const int wm = wave & 1;
    const int wn = wave >> 1;
    const int tm = blockIdx.x * 128;
    const int tn = blockIdx.y * 128;

    // staging: thread -> (row = tid/4, 16B seg = (tid&3)*8 fp16); 2 rounds of 64 rows
    const int srow = tid >> 2;
    const int scol = (tid & 3) * 8;
    const char* gA0 = (const char*)(A  + (size_t)(tm + srow) * DIM + scol);
    const char* gA1 = (const char*)(A  + (size_t)(tm + 64 + srow) * DIM + scol);
    const char* gB0 = (const char*)(Bt + (size_t)(tn + srow) * DIM + scol);
    const char* gB1 = (const char*)(Bt + (size_t)(tn + 64 + srow) * DIM + scol);
    char* lA = (char*)sA + tid * 16;   // lane0 value = wave base; HW adds lane*16
    char* lB = (char*)sB + tid * 16;

    const floatx4 zero = {0.f, 0.f, 0.f, 0.f};
    floatx4 acc[4][4];
    #pragma unroll
    for (int i = 0; i < 4; ++i)
        #pragma unroll
        for (int j = 0; j < 4; ++j) acc[i][j] = zero;

    const int mrow = lane & 15;          // A/B operand free index
    const int kk   = (lane >> 4) * 8;    // k = quad*8 + j

    for (int kt = 0; kt < DIM; kt += 32) {
        g2l16(gA0, lA);
        g2l16(gA1, lA + 4096);
        g2l16(gB0, lB);
        g2l16(gB1, lB + 4096);
        gA0 += 64; gA1 += 64; gB0 += 64; gB1 += 64;   // 32 fp16 = 64 B
        __syncthreads();                               // drains vmcnt before barrier

        half8 af[4], bf[4];
        #pragma unroll
        for (int f = 0; f < 4; ++f)
            af[f] = *(const half8*)(sA + (size_t)(wm * 64 + f * 16 + mrow) * 32 + kk);
        #pragma unroll
        for (int f = 0; f < 4; ++f)
            bf[f] = *(const half8*)(sB + (size_t)(wn * 64 + f * 16 + mrow) * 32 + kk);

        #pragma unroll
        for (int i = 0; i < 4; ++i)
            #pragma unroll
            for (int j = 0; j < 4; ++j)
                acc[i][j] = __builtin_amdgcn_mfma_f32_16x16x32_f16(af[i], bf[j], acc[i][j], 0, 0, 0);
        __syncthreads();
    }

    // C/D layout: col = lane&15 (B-side n), row = (lane>>4)*4 + reg (A-side m)
    const int r0 = (lane >> 4) * 4;
    const int cn = lane & 15;
    #pragma unroll
    for (int i = 0; i < 4; ++i) {
        #pragma unroll
        for (int j = 0; j < 4; ++j) {
            const int row = tm + wm * 64 + i * 16 + r0;
            const int col = tn + wn * 64 + j * 16 + cn;
            #pragma unroll
            for (int r = 0; r < 4; ++r)
                C[(size_t)(row + r) * KDIR + col] = acc[i][j][r];
        }
    }
}

// ---------------------------------------------------------------------------
// K5: per-chunk column sums of proj (64 rows/chunk, 128 chunks).
// pp[ch][0][c] = sum p, pp[ch][1][c] = sum p^2
__global__ __launch_bounds__(256) void stats_p1(const float* __restrict__ proj,
                                                float* __restrict__ pp) {
    const int ch = blockIdx.x >> 1;
    const int c  = (blockIdx.x & 1) * 256 + threadIdx.x;
    const float* p = proj + (size_t)(ch * 64) * KDIR + c;
    float s = 0.f, s2 = 0.f;
    #pragma unroll 4
    for (int r = 0; r < 64; ++r) {
        float v = p[(size_t)r * KDIR];
        s += v;
        s2 = fmaf(v, v, s2);
    }
    pp[(size_t)(ch * 2 + 0) * KDIR + c] = s;
    pp[(size_t)(ch * 2 + 1) * KDIR + c] = s2;
}

// K6: reduce chunks in double -> mu[c], isd[c] = 1/(std_ddof1 + 1e-8)
__global__ __launch_bounds__(256) void stats_p2(const float* __restrict__ pp,
                                                float* __restrict__ mu,
                                                float* __restrict__ isd) {
    const int c = blockIdx.x * 256 + threadIdx.x;
    double s = 0.0, s2 = 0.0;
    for (int ch = 0; ch < 128; ++ch) {
        s  += (double)pp[(size_t)(ch * 2 + 0) * KDIR + c];
        s2 += (double)pp[(size_t)(ch * 2 + 1) * KDIR + c];
    }
    double m   = s / (double)BATCH;
    double var = (s2 - (double)BATCH * m * m) / (double)(BATCH - 1);
    double sd  = sqrt(var) + 1e-8;
    mu[c]  = (float)m;
    isd[c] = (float)(1.0 / sd);
}

// ---------------------------------------------------------------------------
// K7: ECF partials. 32 rows/chunk -> 256 chunks x 2 col-groups = 512 blocks.
// pecf[ch][i][0][c] = sum cos(t_i z), pecf[ch][i][1][c] = sum sin(t_i z)
__global__ __launch_bounds__(256) void ecf_p1(const float* __restrict__ proj,
                                              const float* __restrict__ mu,
                                              const float* __restrict__ isd,
                                              float* __restrict__ pecf) {
    const int ch = blockIdx.x >> 1;
    const int c  = (blockIdx.x & 1) * 256 + threadIdx.x;
    const float m = mu[c];
    const float sdi = isd[c];
    float cr[NPTS], ci[NPTS];
    #pragma unroll
    for (int i = 0; i < NPTS; ++i) { cr[i] = 0.f; ci[i] = 0.f; }
    const float* p = proj + (size_t)(ch * 32) * KDIR + c;
    for (int r = 0; r < 32; ++r) {
        float z = (p[(size_t)r * KDIR] - m) * sdi;
        #pragma unroll
        for (int i = 0; i < NPTS; ++i) {
            float arg = z * ((float)(i + 1) * (2.0f / 17.0f));
            float sn, cs;
            __sincosf(arg, &sn, &cs);
            cr[i] += cs;
            ci[i] += sn;
        }
    }
    #pragma unroll
    for (int i = 0; i < NPTS; ++i) {
        pecf[(size_t)((ch * NPTS + i) * 2 + 0) * KDIR + c] = cr[i];
        pecf[(size_t)((ch * NPTS + i) * 2 + 1) * KDIR + c] = ci[i];
    }
}

// K8: reduce chunks (double), form w_i*((R-tau)^2 + I^2)/K, block-reduce, atomic.
__global__ __launch_bounds__(256) void ecf_p2(const float* __restrict__ pecf,
                                              float* __restrict__ out) {
    const int i = blockIdx.x >> 1;                       // 0..16
    const int c = (blockIdx.x & 1) * 256 + threadIdx.x;  // 0..511
    double sc = 0.0, ss = 0.0;
    for (int ch = 0; ch < 256; ++ch) {
        sc += (double)pecf[(size_t)((ch * NPTS + i) * 2 + 0) * KDIR + c];
        ss += (double)pecf[(size_t)((ch * NPTS + i) * 2 + 1) * KDIR + c];
    }
    const double R = sc / (double)BATCH;
    const double I = ss / (double)BATCH;
    const double t = (2.0 / 17.0) * (double)(i + 1);
    const double tau = exp(-0.5 * t * t);
    const double w = (i == 0 || i == NPTS - 1) ? (1.0 / 17.0) : (2.0 / 17.0);
    const double dR = R - tau;
    double contrib = w * (dR * dR + I * I) / (double)KDIR;

    __shared__ double red[256];
    red[threadIdx.x] = contrib;
    __syncthreads();
    for (int s = 128; s > 0; s >>= 1) {
        if (threadIdx.x < s) red[threadIdx.x] += red[threadIdx.x + s];
        __syncthreads();
    }
    if (threadIdx.x == 0) atomicAdd(out, (float)red[0]);
}

// ---------------------------------------------------------------------------
extern "C" void kernel_launch(void* const* d_in, const int* in_sizes, int n_in,
                              void* d_out, int out_size, void* d_ws, size_t ws_size,
                              hipStream_t stream) {
    const float* emb = (const float*)d_in[0];   // (8192, 2048)
    const float* dir = (const float*)d_in[1];   // (2048, 512)
    float* out = (float*)d_out;

    char* ws = (char*)d_ws;
    // layout (total ~52.4 MB). pecf/stats alias the A16 region (dead after GEMM).
    _Float16* A16  = (_Float16*)(ws + 0);               // 33,554,432 B
    float*    pecf = (float*)   (ws + 0);               // 17,825,792 B (after GEMM)
    float*    pp   = (float*)   (ws + 17825792);        //    524,288 B (after GEMM)
    _Float16* dT   = (_Float16*)(ws + 33554432);        //  2,097,152 B
    float*    proj = (float*)   (ws + 35651584);        // 16,777,216 B
    float*    invn = (float*)   (ws + 52428800);
    float*    mu   = (float*)   (ws + 52432896);
    float*    isd  = (float*)   (ws + 52436992);

    hipMemsetAsync(d_out, 0, sizeof(float), stream);

    col_norms<<<KDIR, 64, 0, stream>>>(dir, invn);
    make_dT<<<dim3(DIM / 64, KDIR / 64), 256, 0, stream>>>(dir, invn, dT);
    cvt_f16<<<(BATCH * DIM) / (256 * 8), 256, 0, stream>>>(emb, A16);
    gemm16<<<dim3(BATCH / 128, KDIR / 128), 256, 0, stream>>>(A16, dT, proj);
    stats_p1<<<256, 256, 0, stream>>>(proj, pp);
    stats_p2<<<2, 256, 0, stream>>>(pp, mu, isd);
    ecf_p1<<<512, 256, 0, stream>>>(proj, mu, isd, pecf);
    ecf_p2<<<34, 256, 0, stream>>>(pecf, out);
}

// Round 2
// 202.464 us; speedup vs baseline: 1.0302x; 1.0302x over previous
//
#include <hip/hip_runtime.h>
#include <hip/hip_bf16.h>
#include <stdint.h>
#include <math.h>

// Problem constants (fixed by setup_inputs)
#define BATCH 8192   // B rows of embeddings
#define DIM   2048   // D feature dim
#define KDIR  512    // K directions
#define NPTS  17     // quadrature points

typedef _Float16 half8  __attribute__((ext_vector_type(8)));
typedef float   floatx4 __attribute__((ext_vector_type(4)));

#define AS1 __attribute__((address_space(1)))
#define AS3 __attribute__((address_space(3)))

// async global->LDS, 16B per lane. LDS dest must be wave-uniform base + lane*16.
__device__ __forceinline__ void g2l16(const void* g, void* l) {
    __builtin_amdgcn_global_load_lds((AS1 void*)(uintptr_t)g, (AS3 void*)l, 16u, 0, 0u);
}

// ---------------------------------------------------------------------------
// K1: column sum-of-squares of directions -> inv_norm[k] = 1/max(||d_k||,1e-12)
__global__ __launch_bounds__(64) void col_norms(const float* __restrict__ dir,
                                                float* __restrict__ invn) {
    const int k = blockIdx.x;
    const int lane = threadIdx.x;
    float s = 0.f;
    for (int r = lane; r < DIM; r += 64) {
        float v = dir[(size_t)r * KDIR + k];
        s = fmaf(v, v, s);
    }
    for (int off = 32; off > 0; off >>= 1) s += __shfl_down(s, off, 64);
    if (lane == 0) invn[k] = 1.0f / fmaxf(sqrtf(s), 1e-12f);
}

// ---------------------------------------------------------------------------
// K2: dT[n][kdim] = fp16( dir[kdim][n] * invn[n] )  -- 64x64 LDS tile transpose
__global__ __launch_bounds__(256) void make_dT(const float* __restrict__ dir,
                                               const float* __restrict__ invn,
                                               _Float16* __restrict__ dT) {
    __shared__ float tile[64][65];
    const int i0 = blockIdx.x * 64;   // DIM
    const int k0 = blockIdx.y * 64;   // KDIR
    const int tid = threadIdx.x;
    #pragma unroll
    for (int it = 0; it < 16; ++it) {
        int idx = tid + it * 256;
        int r = idx >> 6, c = idx & 63;
        tile[c][r] = dir[(size_t)(i0 + r) * KDIR + (k0 + c)] * invn[k0 + c];
    }
    __syncthreads();
    #pragma unroll
    for (int it = 0; it < 16; ++it) {
        int idx = tid + it * 256;
        int c = idx >> 6, i = idx & 63;
        dT[(size_t)(k0 + c) * DIM + (i0 + i)] = (_Float16)tile[c][i];
    }
}

// ---------------------------------------------------------------------------
// K3: embeddings fp32 -> fp16 (8 elems/thread, 32B loads -> 16B store)
__global__ __launch_bounds__(256) void cvt_f16(const float* __restrict__ x,
                                               _Float16* __restrict__ y) {
    const size_t i = ((size_t)blockIdx.x * 256 + threadIdx.x) * 8;
    floatx4 a = *(const floatx4*)(x + i);
    floatx4 b = *(const floatx4*)(x + i + 4);
    half8 h;
    h[0] = (_Float16)a[0]; h[1] = (_Float16)a[1];
    h[2] = (_Float16)a[2]; h[3] = (_Float16)a[3];
    h[4] = (_Float16)b[0]; h[5] = (_Float16)b[1];
    h[6] = (_Float16)b[2]; h[7] = (_Float16)b[3];
    *(half8*)(y + i) = h;
}

// ---------------------------------------------------------------------------
// K4: fp16 MFMA GEMM. BM=128, BN=64, BK=64 (two 32-wide k-halves so LDS rows
// stay 64B = m97-proven conflict profile), split-K=2 -> grid (64,8,2) = 1024
// blocks = 4 blocks/CU. Epilogue: atomicAdd into zeroed C (exactly 2
// commutative fp32 adds per element -> deterministic).
__global__ __launch_bounds__(256, 4) void gemm16(const _Float16* __restrict__ A,
                                                 const _Float16* __restrict__ Bt,
                                                 float* __restrict__ C) {
    __shared__ _Float16 sA0[128 * 32];  // k in [0,32) of current BK=64 slab
    __shared__ _Float16 sA1[128 * 32];  // k in [32,64)
    __shared__ _Float16 sB0[64 * 32];
    __shared__ _Float16 sB1[64 * 32];

    const int tid  = threadIdx.x;
    const int lane = tid & 63;
    const int wave = tid >> 6;
    const int wm = wave & 1;            // 2 wave-rows  (64 each)
    const int wn = wave >> 1;           // 2 wave-cols  (32 each)
    const int tm = blockIdx.x * 128;
    const int tn = blockIdx.y * 64;
    const int k0 = blockIdx.z * (DIM / 2);

    // staging map: row = tid>>2 (64 rows/call), 16B seg = (tid&3)*8 fp16
    const int srow = tid >> 2;
    const int scol = (tid & 3) * 8;
    const _Float16* pA0  = A  + (size_t)(tm + srow) * DIM + k0 + scol;        // rows 0-63
    const _Float16* pA0b = A  + (size_t)(tm + 64 + srow) * DIM + k0 + scol;   // rows 64-127
    const _Float16* pB0  = Bt + (size_t)(tn + srow) * DIM + k0 + scol;
    char* lA0  = (char*)sA0 + tid * 16;          // covers rows 0-63   (4KB)
    char* lA0b = (char*)sA0 + 4096 + tid * 16;   // rows 64-127
    char* lA1  = (char*)sA1 + tid * 16;
    char* lA1b = (char*)sA1 + 4096 + tid * 16;
    char* lB0  = (char*)sB0 + tid * 16;
    char* lB1  = (char*)sB1 + tid * 16;

    const floatx4 zero = {0.f, 0.f, 0.f, 0.f};
    floatx4 acc[4][2];
    #pragma unroll
    for (int i = 0; i < 4; ++i)
        #pragma unroll
        for (int j = 0; j < 2; ++j) acc[i][j] = zero;

    const int mrow = lane & 15;          // operand free index
    const int kk   = (lane >> 4) * 8;    // k = quad*8 + j

    for (int kt = 0; kt < DIM / 2; kt += 64) {
        g2l16(pA0,       lA0);
        g2l16(pA0b,      lA0b);
        g2l16(pA0  + 32, lA1);
        g2l16(pA0b + 32, lA1b);
        g2l16(pB0,       lB0);
        g2l16(pB0  + 32, lB1);
        pA0 += 64; pA0b += 64; pB0 += 64;
        __syncthreads();

        half8 a0[4], a1[4], b0[2], b1[2];
        #pragma unroll
        for (int f = 0; f < 4; ++f) {
            a0[f] = *(const half8*)(sA0 + (size_t)(wm * 64 + f * 16 + mrow) * 32 + kk);
            a1[f] = *(const half8*)(sA1 + (size_t)(wm * 64 + f * 16 + mrow) * 32 + kk);
        }
        #pragma unroll
        for (int j = 0; j < 2; ++j) {
            b0[j] = *(const half8*)(sB0 + (size_t)(wn * 32 + j * 16 + mrow) * 32 + kk);
            b1[j] = *(const half8*)(sB1 + (size_t)(wn * 32 + j * 16 + mrow) * 32 + kk);
        }

        #pragma unroll
        for (int i = 0; i < 4; ++i)
            #pragma unroll
            for (int j = 0; j < 2; ++j) {
                acc[i][j] = __builtin_amdgcn_mfma_f32_16x16x32_f16(a0[i], b0[j], acc[i][j], 0, 0, 0);
                acc[i][j] = __builtin_amdgcn_mfma_f32_16x16x32_f16(a1[i], b1[j], acc[i][j], 0, 0, 0);
            }
        __syncthreads();
    }

    // C/D layout: col = lane&15, row = (lane>>4)*4 + reg
    const int r0 = (lane >> 4) * 4;
    const int cn = lane & 15;
    #pragma unroll
    for (int i = 0; i < 4; ++i) {
        #pragma unroll
        for (int j = 0; j < 2; ++j) {
            const int row = tm + wm * 64 + i * 16 + r0;
            const int col = tn + wn * 32 + j * 16 + cn;
            #pragma unroll
            for (int r = 0; r < 4; ++r)
                atomicAdd(&C[(size_t)(row + r) * KDIR + col], acc[i][j][r]);
        }
    }
}

// ---------------------------------------------------------------------------
// K5: per-chunk column sums of proj (64 rows/chunk, 128 chunks).
__global__ __launch_bounds__(256) void stats_p1(const float* __restrict__ proj,
                                                float* __restrict__ pp) {
    const int ch = blockIdx.x >> 1;
    const int c  = (blockIdx.x & 1) * 256 + threadIdx.x;
    const float* p = proj + (size_t)(ch * 64) * KDIR + c;
    float s = 0.f, s2 = 0.f;
    #pragma unroll 4
    for (int r = 0; r < 64; ++r) {
        float v = p[(size_t)r * KDIR];
        s += v;
        s2 = fmaf(v, v, s2);
    }
    pp[(size_t)(ch * 2 + 0) * KDIR + c] = s;
    pp[(size_t)(ch * 2 + 1) * KDIR + c] = s2;
}

// K6: reduce 128 chunks (double) -> mu[c], isd[c]. 16 blocks x (32 c x 8 grp).
__global__ __launch_bounds__(256) void stats_p2(const float* __restrict__ pp,
                                                float* __restrict__ mu,
                                                float* __restrict__ isd) {
    const int tid = threadIdx.x;
    const int cl  = tid & 31;
    const int g   = tid >> 5;            // 8 groups of 16 chunks
    const int c   = blockIdx.x * 32 + cl;
    double s = 0.0, s2 = 0.0;
    for (int ch = g * 16; ch < g * 16 + 16; ++ch) {
        s  += (double)pp[(size_t)(ch * 2 + 0) * KDIR + c];
        s2 += (double)pp[(size_t)(ch * 2 + 1) * KDIR + c];
    }
    __shared__ double rs[8][32], rq[8][32];
    rs[g][cl] = s; rq[g][cl] = s2;
    __syncthreads();
    if (tid < 32) {
        double ts = 0.0, tq = 0.0;
        #pragma unroll
        for (int gg = 0; gg < 8; ++gg) { ts += rs[gg][tid]; tq += rq[gg][tid]; }
        double m   = ts / (double)BATCH;
        double var = (tq - (double)BATCH * m * m) / (double)(BATCH - 1);
        double sd  = sqrt(var) + 1e-8;
        mu[blockIdx.x * 32 + tid]  = (float)m;
        isd[blockIdx.x * 32 + tid] = (float)(1.0 / sd);
    }
}

// ---------------------------------------------------------------------------
// K7: ECF partials. 32 rows/chunk -> 256 chunks x 2 col-groups = 512 blocks.
__global__ __launch_bounds__(256) void ecf_p1(const float* __restrict__ proj,
                                              const float* __restrict__ mu,
                                              const float* __restrict__ isd,
                                              float* __restrict__ pecf) {
    const int ch = blockIdx.x >> 1;
    const int c  = (blockIdx.x & 1) * 256 + threadIdx.x;
    const float m = mu[c];
    const float sdi = isd[c];
    float cr[NPTS], ci[NPTS];
    #pragma unroll
    for (int i = 0; i < NPTS; ++i) { cr[i] = 0.f; ci[i] = 0.f; }
    const float* p = proj + (size_t)(ch * 32) * KDIR + c;
    for (int r = 0; r < 32; ++r) {
        float z = (p[(size_t)r * KDIR] - m) * sdi;
        #pragma unroll
        for (int i = 0; i < NPTS; ++i) {
            float arg = z * ((float)(i + 1) * (2.0f / 17.0f));
            float sn, cs;
            __sincosf(arg, &sn, &cs);
            cr[i] += cs;
            ci[i] += sn;
        }
    }
    #pragma unroll
    for (int i = 0; i < NPTS; ++i) {
        pecf[(size_t)((ch * NPTS + i) * 2 + 0) * KDIR + c] = cr[i];
        pecf[(size_t)((ch * NPTS + i) * 2 + 1) * KDIR + c] = ci[i];
    }
}

// K8a: first-stage chunk reduce: 272 blocks = 17 i x (2 halves x 8 groups).
// Each block sums 32 chunks for 256 c's -> pec2 (double).
__global__ __launch_bounds__(256) void ecf_p2a(const float* __restrict__ pecf,
                                               double* __restrict__ pec2) {
    const int b = blockIdx.x;
    const int i = b >> 4;
    const int r = b & 15;
    const int half = r & 1;
    const int g = r >> 1;                 // 8 groups of 32 chunks
    const int c = half * 256 + threadIdx.x;
    double sc = 0.0, ss = 0.0;
    for (int ch = g * 32; ch < g * 32 + 32; ++ch) {
        sc += (double)pecf[(size_t)((ch * NPTS + i) * 2 + 0) * KDIR + c];
        ss += (double)pecf[(size_t)((ch * NPTS + i) * 2 + 1) * KDIR + c];
    }
    pec2[(size_t)((i * 8 + g) * 2 + 0) * KDIR + c] = sc;
    pec2[(size_t)((i * 8 + g) * 2 + 1) * KDIR + c] = ss;
}

// K8b: finish: sum 8 groups, form w_i*((R-tau)^2 + I^2)/K, block-reduce, atomic.
__global__ __launch_bounds__(256) void ecf_p2b(const double* __restrict__ pec2,
                                               float* __restrict__ out) {
    const int i = blockIdx.x >> 1;
    const int c = (blockIdx.x & 1) * 256 + threadIdx.x;
    double sc = 0.0, ss = 0.0;
    #pragma unroll
    for (int g = 0; g < 8; ++g) {
        sc += pec2[(size_t)((i * 8 + g) * 2 + 0) * KDIR + c];
        ss += pec2[(size_t)((i * 8 + g) * 2 + 1) * KDIR + c];
    }
    const double R = sc / (double)BATCH;
    const double I = ss / (double)BATCH;
    const double t = (2.0 / 17.0) * (double)(i + 1);
    const double tau = exp(-0.5 * t * t);
    const double w = (i == 0 || i == NPTS - 1) ? (1.0 / 17.0) : (2.0 / 17.0);
    const double dR = R - tau;
    double contrib = w * (dR * dR + I * I) / (double)KDIR;

    __shared__ double red[256];
    red[threadIdx.x] = contrib;
    __syncthreads();
    for (int s = 128; s > 0; s >>= 1) {
        if (threadIdx.x < s) red[threadIdx.x] += red[threadIdx.x + s];
        __syncthreads();
    }
    if (threadIdx.x == 0) atomicAdd(out, (float)red[0]);
}

// ---------------------------------------------------------------------------
extern "C" void kernel_launch(void* const* d_in, const int* in_sizes, int n_in,
                              void* d_out, int out_size, void* d_ws, size_t ws_size,
                              hipStream_t stream) {
    const float* emb = (const float*)d_in[0];   // (8192, 2048)
    const float* dir = (const float*)d_in[1];   // (2048, 512)
    float* out = (float*)d_out;

    char* ws = (char*)d_ws;
    // layout. pecf/pp/pec2 alias the A16 region (dead after GEMM).
    _Float16* A16  = (_Float16*)(ws + 0);               // 33,554,432 B
    float*    pecf = (float*)   (ws + 0);               // 17,825,792 B (after GEMM)
    float*    pp   = (float*)   (ws + 17825792);        //    524,288 B (after GEMM)
    double*   pec2 = (double*)  (ws + 18350080);        //  1,114,112 B (after GEMM)
    _Float16* dT   = (_Float16*)(ws + 33554432);        //  2,097,152 B
    float*    proj = (float*)   (ws + 35651584);        // 16,777,216 B
    float*    invn = (float*)   (ws + 52428800);
    float*    mu   = (float*)   (ws + 52432896);
    float*    isd  = (float*)   (ws + 52436992);

    hipMemsetAsync(d_out, 0, sizeof(float), stream);
    hipMemsetAsync(proj, 0, (size_t)BATCH * KDIR * sizeof(float), stream);  // split-K atomic target

    col_norms<<<KDIR, 64, 0, stream>>>(dir, invn);
    make_dT<<<dim3(DIM / 64, KDIR / 64), 256, 0, stream>>>(dir, invn, dT);
    cvt_f16<<<(BATCH * DIM) / (256 * 8), 256, 0, stream>>>(emb, A16);
    gemm16<<<dim3(BATCH / 128, KDIR / 64, 2), 256, 0, stream>>>(A16, dT, proj);
    stats_p1<<<256, 256, 0, stream>>>(proj, pp);
    stats_p2<<<16, 256, 0, stream>>>(pp, mu, isd);
    ecf_p1<<<512, 256, 0, stream>>>(proj, mu, isd, pecf);
    ecf_p2a<<<272, 256, 0, stream>>>(pecf, pec2);
    ecf_p2b<<<34, 256, 0, stream>>>(pec2, out);
}

// Round 3
// 200.349 us; speedup vs baseline: 1.0410x; 1.0106x over previous
//
#include <hip/hip_runtime.h>
#include <hip/hip_bf16.h>
#include <stdint.h>
#include <math.h>

// Problem constants (fixed by setup_inputs)
#define BATCH 8192   // B rows of embeddings
#define DIM   2048   // D feature dim
#define KDIR  512    // K directions
#define NPTS  17     // quadrature points

typedef _Float16 half8  __attribute__((ext_vector_type(8)));
typedef float   floatx4 __attribute__((ext_vector_type(4)));

#define AS1 __attribute__((address_space(1)))
#define AS3 __attribute__((address_space(3)))

// async global->LDS, 16B per lane. LDS dest must be wave-uniform base + lane*16.
__device__ __forceinline__ void g2l16(const void* g, void* l) {
    __builtin_amdgcn_global_load_lds((AS1 void*)(uintptr_t)g, (AS3 void*)l, 16u, 0, 0u);
}

// ---------------------------------------------------------------------------
// K1: fused normalize + transpose. One block per direction column k:
// reduce sum-of-squares of dir[:,k], then write dT[k][0:2048] = fp16(v/||.||).
// Thread t owns 8 consecutive rows r = t*8..t*8+7 -> vector half8 store.
__global__ __launch_bounds__(256) void norm_dT(const float* __restrict__ dir,
                                               _Float16* __restrict__ dT) {
    const int k = blockIdx.x;
    const int t = threadIdx.x;
    float v[8];
    float s = 0.f;
    #pragma unroll
    for (int i = 0; i < 8; ++i) {
        v[i] = dir[(size_t)(t * 8 + i) * KDIR + k];
        s = fmaf(v[i], v[i], s);
    }
    // wave reduce
    for (int off = 32; off > 0; off >>= 1) s += __shfl_down(s, off, 64);
    __shared__ float ws_[4];
    if ((t & 63) == 0) ws_[t >> 6] = s;
    __syncthreads();
    const float inv = 1.0f / fmaxf(sqrtf(ws_[0] + ws_[1] + ws_[2] + ws_[3]), 1e-12f);
    half8 h;
    #pragma unroll
    for (int i = 0; i < 8; ++i) h[i] = (_Float16)(v[i] * inv);
    *(half8*)(dT + (size_t)k * DIM + t * 8) = h;
}

// ---------------------------------------------------------------------------
// K2: embeddings fp32 -> fp16 (8 elems/thread, 32B loads -> 16B store)
__global__ __launch_bounds__(256) void cvt_f16(const float* __restrict__ x,
                                               _Float16* __restrict__ y) {
    const size_t i = ((size_t)blockIdx.x * 256 + threadIdx.x) * 8;
    floatx4 a = *(const floatx4*)(x + i);
    floatx4 b = *(const floatx4*)(x + i + 4);
    half8 h;
    h[0] = (_Float16)a[0]; h[1] = (_Float16)a[1];
    h[2] = (_Float16)a[2]; h[3] = (_Float16)a[3];
    h[4] = (_Float16)b[0]; h[5] = (_Float16)b[1];
    h[6] = (_Float16)b[2]; h[7] = (_Float16)b[3];
    *(half8*)(y + i) = h;
}

// ---------------------------------------------------------------------------
// K3: fp16 MFMA GEMM, m97-exact tile: 128x128, BK=32, 4 waves 2x2, wave tile
// 64x64 (4x4 frags) -> 8 ds_read_b128 + 4 g2l per block-iter per 1.05 MFLOP.
// split-K=2 -> grid (64,4,2) = 512 blocks. Epilogue atomicAdd into zeroed C
// (exactly 2 commutative fp32 adds per element -> deterministic).
__global__ __launch_bounds__(256, 4) void gemm16(const _Float16* __restrict__ A,
                                                 const _Float16* __restrict__ Bt,
                                                 float* __restrict__ C) {
    __shared__ _Float16 sA[128 * 32];   // [m][k], 64B rows (m97-proven profile)
    __shared__ _Float16 sB[128 * 32];

    const int tid  = threadIdx.x;
    const int lane = tid & 63;
    const int wave = tid >> 6;
    const int wm = wave & 1;            // 2 wave-rows (64 each)
    const int wn = wave >> 1;           // 2 wave-cols (64 each)
    const int tm = blockIdx.x * 128;
    const int tn = blockIdx.y * 128;
    const int k0 = blockIdx.z * (DIM / 2);

    // staging map: row = tid>>2 (64 rows/call), 16B seg = (tid&3)*8 fp16
    const int srow = tid >> 2;
    const int scol = (tid & 3) * 8;
    const _Float16* pA0 = A  + (size_t)(tm + srow) * DIM + k0 + scol;
    const _Float16* pA1 = A  + (size_t)(tm + 64 + srow) * DIM + k0 + scol;
    const _Float16* pB0 = Bt + (size_t)(tn + srow) * DIM + k0 + scol;
    const _Float16* pB1 = Bt + (size_t)(tn + 64 + srow) * DIM + k0 + scol;
    char* lA0 = (char*)sA + tid * 16;
    char* lA1 = (char*)sA + 4096 + tid * 16;
    char* lB0 = (char*)sB + tid * 16;
    char* lB1 = (char*)sB + 4096 + tid * 16;

    const floatx4 zero = {0.f, 0.f, 0.f, 0.f};
    floatx4 acc[4][4];
    #pragma unroll
    for (int i = 0; i < 4; ++i)
        #pragma unroll
        for (int j = 0; j < 4; ++j) acc[i][j] = zero;

    const int mrow = lane & 15;          // operand free index
    const int kk   = (lane >> 4) * 8;    // k = quad*8 + j

    for (int kt = 0; kt < DIM / 2; kt += 32) {
        g2l16(pA0, lA0);
        g2l16(pA1, lA1);
        g2l16(pB0, lB0);
        g2l16(pB1, lB1);
        pA0 += 32; pA1 += 32; pB0 += 32; pB1 += 32;
        __syncthreads();

        half8 af[4], bf[4];
        #pragma unroll
        for (int f = 0; f < 4; ++f)
            af[f] = *(const half8*)(sA + (size_t)(wm * 64 + f * 16 + mrow) * 32 + kk);
        #pragma unroll
        for (int f = 0; f < 4; ++f)
            bf[f] = *(const half8*)(sB + (size_t)(wn * 64 + f * 16 + mrow) * 32 + kk);

        #pragma unroll
        for (int i = 0; i < 4; ++i)
            #pragma unroll
            for (int j = 0; j < 4; ++j)
                acc[i][j] = __builtin_amdgcn_mfma_f32_16x16x32_f16(af[i], bf[j], acc[i][j], 0, 0, 0);
        __syncthreads();
    }

    // C/D layout: col = lane&15, row = (lane>>4)*4 + reg
    const int r0 = (lane >> 4) * 4;
    const int cn = lane & 15;
    #pragma unroll
    for (int i = 0; i < 4; ++i) {
        #pragma unroll
        for (int j = 0; j < 4; ++j) {
            const int row = tm + wm * 64 + i * 16 + r0;
            const int col = tn + wn * 64 + j * 16 + cn;
            #pragma unroll
            for (int r = 0; r < 4; ++r)
                atomicAdd(&C[(size_t)(row + r) * KDIR + col], acc[i][j][r]);
        }
    }
}

// ---------------------------------------------------------------------------
// K4: per-chunk column sums of proj (64 rows/chunk, 128 chunks).
__global__ __launch_bounds__(256) void stats_p1(const float* __restrict__ proj,
                                                float* __restrict__ pp) {
    const int ch = blockIdx.x >> 1;
    const int c  = (blockIdx.x & 1) * 256 + threadIdx.x;
    const float* p = proj + (size_t)(ch * 64) * KDIR + c;
    float s = 0.f, s2 = 0.f;
    #pragma unroll 4
    for (int r = 0; r < 64; ++r) {
        float v = p[(size_t)r * KDIR];
        s += v;
        s2 = fmaf(v, v, s2);
    }
    pp[(size_t)(ch * 2 + 0) * KDIR + c] = s;
    pp[(size_t)(ch * 2 + 1) * KDIR + c] = s2;
}

// K5: reduce 128 chunks (double) -> mu[c], isd[c]. 16 blocks x (32 c x 8 grp).
__global__ __launch_bounds__(256) void stats_p2(const float* __restrict__ pp,
                                                float* __restrict__ mu,
                                                float* __restrict__ isd) {
    const int tid = threadIdx.x;
    const int cl  = tid & 31;
    const int g   = tid >> 5;            // 8 groups of 16 chunks
    const int c   = blockIdx.x * 32 + cl;
    double s = 0.0, s2 = 0.0;
    for (int ch = g * 16; ch < g * 16 + 16; ++ch) {
        s  += (double)pp[(size_t)(ch * 2 + 0) * KDIR + c];
        s2 += (double)pp[(size_t)(ch * 2 + 1) * KDIR + c];
    }
    __shared__ double rs[8][32], rq[8][32];
    rs[g][cl] = s; rq[g][cl] = s2;
    __syncthreads();
    if (tid < 32) {
        double ts = 0.0, tq = 0.0;
        #pragma unroll
        for (int gg = 0; gg < 8; ++gg) { ts += rs[gg][tid]; tq += rq[gg][tid]; }
        double m   = ts / (double)BATCH;
        double var = (tq - (double)BATCH * m * m) / (double)(BATCH - 1);
        double sd  = sqrt(var) + 1e-8;
        mu[blockIdx.x * 32 + tid]  = (float)m;
        isd[blockIdx.x * 32 + tid] = (float)(1.0 / sd);
    }
}

// ---------------------------------------------------------------------------
// K6: ECF partials. 32 rows/chunk -> 256 chunks x 2 col-groups = 512 blocks.
__global__ __launch_bounds__(256) void ecf_p1(const float* __restrict__ proj,
                                              const float* __restrict__ mu,
                                              const float* __restrict__ isd,
                                              float* __restrict__ pecf) {
    const int ch = blockIdx.x >> 1;
    const int c  = (blockIdx.x & 1) * 256 + threadIdx.x;
    const float m = mu[c];
    const float sdi = isd[c];
    float cr[NPTS], ci[NPTS];
    #pragma unroll
    for (int i = 0; i < NPTS; ++i) { cr[i] = 0.f; ci[i] = 0.f; }
    const float* p = proj + (size_t)(ch * 32) * KDIR + c;
    for (int r = 0; r < 32; ++r) {
        float z = (p[(size_t)r * KDIR] - m) * sdi;
        #pragma unroll
        for (int i = 0; i < NPTS; ++i) {
            float arg = z * ((float)(i + 1) * (2.0f / 17.0f));
            float sn, cs;
            __sincosf(arg, &sn, &cs);
            cr[i] += cs;
            ci[i] += sn;
        }
    }
    #pragma unroll
    for (int i = 0; i < NPTS; ++i) {
        pecf[(size_t)((ch * NPTS + i) * 2 + 0) * KDIR + c] = cr[i];
        pecf[(size_t)((ch * NPTS + i) * 2 + 1) * KDIR + c] = ci[i];
    }
}

// K7a: first-stage chunk reduce: 272 blocks = 17 i x (2 halves x 8 groups).
__global__ __launch_bounds__(256) void ecf_p2a(const float* __restrict__ pecf,
                                               double* __restrict__ pec2) {
    const int b = blockIdx.x;
    const int i = b >> 4;
    const int r = b & 15;
    const int half = r & 1;
    const int g = r >> 1;                 // 8 groups of 32 chunks
    const int c = half * 256 + threadIdx.x;
    double sc = 0.0, ss = 0.0;
    for (int ch = g * 32; ch < g * 32 + 32; ++ch) {
        sc += (double)pecf[(size_t)((ch * NPTS + i) * 2 + 0) * KDIR + c];
        ss += (double)pecf[(size_t)((ch * NPTS + i) * 2 + 1) * KDIR + c];
    }
    pec2[(size_t)((i * 8 + g) * 2 + 0) * KDIR + c] = sc;
    pec2[(size_t)((i * 8 + g) * 2 + 1) * KDIR + c] = ss;
}

// K7b: finish: sum 8 groups, form w_i*((R-tau)^2 + I^2)/K, block-reduce, atomic.
__global__ __launch_bounds__(256) void ecf_p2b(const double* __restrict__ pec2,
                                               float* __restrict__ out) {
    const int i = blockIdx.x >> 1;
    const int c = (blockIdx.x & 1) * 256 + threadIdx.x;
    double sc = 0.0, ss = 0.0;
    #pragma unroll
    for (int g = 0; g < 8; ++g) {
        sc += pec2[(size_t)((i * 8 + g) * 2 + 0) * KDIR + c];
        ss += pec2[(size_t)((i * 8 + g) * 2 + 1) * KDIR + c];
    }
    const double R = sc / (double)BATCH;
    const double I = ss / (double)BATCH;
    const double t = (2.0 / 17.0) * (double)(i + 1);
    const double tau = exp(-0.5 * t * t);
    const double w = (i == 0 || i == NPTS - 1) ? (1.0 / 17.0) : (2.0 / 17.0);
    const double dR = R - tau;
    double contrib = w * (dR * dR + I * I) / (double)KDIR;

    __shared__ double red[256];
    red[threadIdx.x] = contrib;
    __syncthreads();
    for (int s = 128; s > 0; s >>= 1) {
        if (threadIdx.x < s) red[threadIdx.x] += red[threadIdx.x + s];
        __syncthreads();
    }
    if (threadIdx.x == 0) atomicAdd(out, (float)red[0]);
}

// ---------------------------------------------------------------------------
extern "C" void kernel_launch(void* const* d_in, const int* in_sizes, int n_in,
                              void* d_out, int out_size, void* d_ws, size_t ws_size,
                              hipStream_t stream) {
    const float* emb = (const float*)d_in[0];   // (8192, 2048)
    const float* dir = (const float*)d_in[1];   // (2048, 512)
    float* out = (float*)d_out;

    char* ws = (char*)d_ws;
    // layout. pecf/pp/pec2 alias the A16 region (dead after GEMM).
    _Float16* A16  = (_Float16*)(ws + 0);               // 33,554,432 B
    float*    pecf = (float*)   (ws + 0);               // 17,825,792 B (after GEMM)
    float*    pp   = (float*)   (ws + 17825792);        //    524,288 B (after GEMM)
    double*   pec2 = (double*)  (ws + 18350080);        //  1,114,112 B (after GEMM)
    _Float16* dT   = (_Float16*)(ws + 33554432);        //  2,097,152 B
    float*    proj = (float*)   (ws + 35651584);        // 16,777,216 B
    float*    mu   = (float*)   (ws + 52428800);
    float*    isd  = (float*)   (ws + 52432896);

    hipMemsetAsync(d_out, 0, sizeof(float), stream);
    hipMemsetAsync(proj, 0, (size_t)BATCH * KDIR * sizeof(float), stream);  // split-K atomic target

    norm_dT<<<KDIR, 256, 0, stream>>>(dir, dT);
    cvt_f16<<<(BATCH * DIM) / (256 * 8), 256, 0, stream>>>(emb, A16);
    gemm16<<<dim3(BATCH / 128, KDIR / 128, 2), 256, 0, stream>>>(A16, dT, proj);
    stats_p1<<<256, 256, 0, stream>>>(proj, pp);
    stats_p2<<<16, 256, 0, stream>>>(pp, mu, isd);
    ecf_p1<<<512, 256, 0, stream>>>(proj, mu, isd, pecf);
    ecf_p2a<<<272, 256, 0, stream>>>(pecf, pec2);
    ecf_p2b<<<34, 256, 0, stream>>>(pec2, out);
}

// Round 4
// 196.632 us; speedup vs baseline: 1.0607x; 1.0189x over previous
//
#include <hip/hip_runtime.h>
#include <hip/hip_bf16.h>
#include <stdint.h>
#include <math.h>

// Problem constants (fixed by setup_inputs)
#define BATCH 8192   // B rows of embeddings
#define DIM   2048   // D feature dim
#define KDIR  512    // K directions
#define NPTS  17     // quadrature points

typedef _Float16 half8  __attribute__((ext_vector_type(8)));
typedef float   floatx4 __attribute__((ext_vector_type(4)));

#define AS1 __attribute__((address_space(1)))
#define AS3 __attribute__((address_space(3)))

// async global->LDS, 16B per lane. LDS dest must be wave-uniform base + lane*16.
__device__ __forceinline__ void g2l16(const void* g, void* l) {
    __builtin_amdgcn_global_load_lds((AS1 void*)(uintptr_t)g, (AS3 void*)l, 16u, 0, 0u);
}

// ---------------------------------------------------------------------------
// K1: fused normalize + transpose. One block per direction column k.
__global__ __launch_bounds__(256) void norm_dT(const float* __restrict__ dir,
                                               _Float16* __restrict__ dT) {
    const int k = blockIdx.x;
    const int t = threadIdx.x;
    float v[8];
    float s = 0.f;
    #pragma unroll
    for (int i = 0; i < 8; ++i) {
        v[i] = dir[(size_t)(t * 8 + i) * KDIR + k];
        s = fmaf(v[i], v[i], s);
    }
    for (int off = 32; off > 0; off >>= 1) s += __shfl_down(s, off, 64);
    __shared__ float ws_[4];
    if ((t & 63) == 0) ws_[t >> 6] = s;
    __syncthreads();
    const float inv = 1.0f / fmaxf(sqrtf(ws_[0] + ws_[1] + ws_[2] + ws_[3]), 1e-12f);
    half8 h;
    #pragma unroll
    for (int i = 0; i < 8; ++i) h[i] = (_Float16)(v[i] * inv);
    *(half8*)(dT + (size_t)k * DIM + t * 8) = h;
}

// ---------------------------------------------------------------------------
// K2: embeddings fp32 -> fp16
__global__ __launch_bounds__(256) void cvt_f16(const float* __restrict__ x,
                                               _Float16* __restrict__ y) {
    const size_t i = ((size_t)blockIdx.x * 256 + threadIdx.x) * 8;
    floatx4 a = *(const floatx4*)(x + i);
    floatx4 b = *(const floatx4*)(x + i + 4);
    half8 h;
    h[0] = (_Float16)a[0]; h[1] = (_Float16)a[1];
    h[2] = (_Float16)a[2]; h[3] = (_Float16)a[3];
    h[4] = (_Float16)b[0]; h[5] = (_Float16)b[1];
    h[6] = (_Float16)b[2]; h[7] = (_Float16)b[3];
    *(half8*)(y + i) = h;
}

// ---------------------------------------------------------------------------
// K3: fp16 MFMA GEMM, software-pipelined. 128x128 tile, BK=64 (two 32-wide
// panels, 64B LDS rows), double-buffered LDS (64 KB), raw s_barrier +
// s_waitcnt vmcnt(8): stage k+1's 8 g2l/wave stay in flight across the
// barrier while stage k computes. Grid (64,4) = 256 blocks, 32 iters.
// Epilogue: plain C stores + fused column sum/sumsq atomics into pp[1024].
__global__ __launch_bounds__(256) void gemm16(const _Float16* __restrict__ A,
                                              const _Float16* __restrict__ Bt,
                                              float* __restrict__ C,
                                              float* __restrict__ pp) {
    __shared__ _Float16 sA[2][2][128 * 32];   // [stage][panel][m][k] 8KB each
    __shared__ _Float16 sB[2][2][128 * 32];

    const int tid  = threadIdx.x;
    const int lane = tid & 63;
    const int wave = tid >> 6;
    const int wm = wave & 1;
    const int wn = wave >> 1;
    const int tm = blockIdx.x * 128;
    const int tn = blockIdx.y * 128;

    // staging map: row = tid>>2 (64 rows/pass), 16B seg = (tid&3)*8 fp16
    const int srow = tid >> 2;
    const int scol = (tid & 3) * 8;
    const _Float16* baseA = A  + (size_t)(tm + srow) * DIM + scol;
    const _Float16* baseB = Bt + (size_t)(tn + srow) * DIM + scol;

#define ISSUE(IT, ST)                                                         \
    do {                                                                      \
        const _Float16* pa = baseA + (IT) * 64;                               \
        const _Float16* pb = baseB + (IT) * 64;                               \
        g2l16(pa,                 (char*)&sA[ST][0][0] + tid * 16);           \
        g2l16(pa + 64 * DIM,      (char*)&sA[ST][0][0] + 4096 + tid * 16);    \
        g2l16(pa + 32,            (char*)&sA[ST][1][0] + tid * 16);           \
        g2l16(pa + 64 * DIM + 32, (char*)&sA[ST][1][0] + 4096 + tid * 16);    \
        g2l16(pb,                 (char*)&sB[ST][0][0] + tid * 16);           \
        g2l16(pb + 64 * DIM,      (char*)&sB[ST][0][0] + 4096 + tid * 16);    \
        g2l16(pb + 32,            (char*)&sB[ST][1][0] + tid * 16);           \
        g2l16(pb + 64 * DIM + 32, (char*)&sB[ST][1][0] + 4096 + tid * 16);    \
    } while (0)

    const floatx4 zero = {0.f, 0.f, 0.f, 0.f};
    floatx4 acc[4][4];
    #pragma unroll
    for (int i = 0; i < 4; ++i)
        #pragma unroll
        for (int j = 0; j < 4; ++j) acc[i][j] = zero;

    const int mrow = lane & 15;
    const int kk   = (lane >> 4) * 8;

    ISSUE(0, 0);                                   // prologue: stage 0 in flight

    const int NIT = DIM / 64;                      // 32
    for (int it = 0; it < NIT; ++it) {
        const int s = it & 1;
        if (it + 1 < NIT) {
            ISSUE(it + 1, (it + 1) & 1);           // 8 more g2l per wave
            asm volatile("s_waitcnt vmcnt(8)" ::: "memory");   // stage `it` landed
        } else {
            asm volatile("s_waitcnt vmcnt(0)" ::: "memory");
        }
        asm volatile("s_barrier" ::: "memory");    // stage `it` visible to all

        half8 a0[4], a1[4], b0[4], b1[4];
        #pragma unroll
        for (int f = 0; f < 4; ++f) {
            a0[f] = *(const half8*)(&sA[s][0][(size_t)(wm * 64 + f * 16 + mrow) * 32 + kk]);
            a1[f] = *(const half8*)(&sA[s][1][(size_t)(wm * 64 + f * 16 + mrow) * 32 + kk]);
            b0[f] = *(const half8*)(&sB[s][0][(size_t)(wn * 64 + f * 16 + mrow) * 32 + kk]);
            b1[f] = *(const half8*)(&sB[s][1][(size_t)(wn * 64 + f * 16 + mrow) * 32 + kk]);
        }
        #pragma unroll
        for (int i = 0; i < 4; ++i)
            #pragma unroll
            for (int j = 0; j < 4; ++j) {
                acc[i][j] = __builtin_amdgcn_mfma_f32_16x16x32_f16(a0[i], b0[j], acc[i][j], 0, 0, 0);
                acc[i][j] = __builtin_amdgcn_mfma_f32_16x16x32_f16(a1[i], b1[j], acc[i][j], 0, 0, 0);
            }
        asm volatile("s_waitcnt lgkmcnt(0)" ::: "memory");  // my ds_reads done
        asm volatile("s_barrier" ::: "memory");    // safe to overwrite stage `it`
    }
#undef ISSUE

    // C/D layout: col = lane&15, row = (lane>>4)*4 + reg
    const int r0 = (lane >> 4) * 4;
    const int cn = lane & 15;
    #pragma unroll
    for (int i = 0; i < 4; ++i) {
        #pragma unroll
        for (int j = 0; j < 4; ++j) {
            const int row = tm + wm * 64 + i * 16 + r0;
            const int col = tn + wn * 64 + j * 16 + cn;
            #pragma unroll
            for (int r = 0; r < 4; ++r)
                C[(size_t)(row + r) * KDIR + col] = acc[i][j][r];
        }
    }

    // fused column stats: per wave, per j-frag: per-lane sum over its 16 rows,
    // reduce across quads (lanes +32, +16), lanes 0-15 atomicAdd to pp.
    #pragma unroll
    for (int j = 0; j < 4; ++j) {
        float s = 0.f, q = 0.f;
        #pragma unroll
        for (int i = 0; i < 4; ++i)
            #pragma unroll
            for (int r = 0; r < 4; ++r) {
                float v = acc[i][j][r];
                s += v;
                q = fmaf(v, v, q);
            }
        s += __shfl_down(s, 32, 64); q += __shfl_down(q, 32, 64);
        s += __shfl_down(s, 16, 64); q += __shfl_down(q, 16, 64);
        if (lane < 16) {
            const int col = tn + wn * 64 + j * 16 + lane;
            atomicAdd(&pp[col], s);
            atomicAdd(&pp[KDIR + col], q);
        }
    }
}

// ---------------------------------------------------------------------------
// K4: finalize stats (double) -> mu[c], isd[c]. One block of 512.
__global__ __launch_bounds__(512) void stats_p2(const float* __restrict__ pp,
                                                float* __restrict__ mu,
                                                float* __restrict__ isd) {
    const int c = threadIdx.x;
    double s  = (double)pp[c];
    double s2 = (double)pp[KDIR + c];
    double m   = s / (double)BATCH;
    double var = (s2 - (double)BATCH * m * m) / (double)(BATCH - 1);
    double sd  = sqrt(var) + 1e-8;
    mu[c]  = (float)m;
    isd[c] = (float)(1.0 / sd);
}

// ---------------------------------------------------------------------------
// K5: ECF partials via angle-addition recurrence: one __sincosf per element,
// then c_{k+1} = c_k c1 - s_k s1. 64 rows/chunk -> 128 chunks x 2 halves.
__global__ __launch_bounds__(256) void ecf_p1(const float* __restrict__ proj,
                                              const float* __restrict__ mu,
                                              const float* __restrict__ isd,
                                              float* __restrict__ pecf) {
    const int ch = blockIdx.x >> 1;                      // 0..127
    const int c  = (blockIdx.x & 1) * 256 + threadIdx.x; // 0..511
    const float m = mu[c];
    const float sdi = isd[c];
    float cr[NPTS], ci[NPTS];
    #pragma unroll
    for (int i = 0; i < NPTS; ++i) { cr[i] = 0.f; ci[i] = 0.f; }
    const float* p = proj + (size_t)(ch * 64) * KDIR + c;
    for (int r = 0; r < 64; ++r) {
        float z = (p[(size_t)r * KDIR] - m) * sdi;
        float a = z * (2.0f / 17.0f);                    // t_1 * z
        float s1, c1;
        __sincosf(a, &s1, &c1);
        float ck = c1, sk = s1;
        cr[0] += c1; ci[0] += s1;
        #pragma unroll
        for (int k = 1; k < NPTS; ++k) {
            float cn_ = ck * c1 - sk * s1;
            float sn_ = sk * c1 + ck * s1;
            ck = cn_; sk = sn_;
            cr[k] += ck; ci[k] += sk;
        }
    }
    #pragma unroll
    for (int i = 0; i < NPTS; ++i) {
        pecf[(size_t)((ch * NPTS + i) * 2 + 0) * KDIR + c] = cr[i];
        pecf[(size_t)((ch * NPTS + i) * 2 + 1) * KDIR + c] = ci[i];
    }
}

// K6a: first-stage chunk reduce: 272 blocks = 17 i x (2 halves x 8 groups of 16).
__global__ __launch_bounds__(256) void ecf_p2a(const float* __restrict__ pecf,
                                               double* __restrict__ pec2) {
    const int b = blockIdx.x;
    const int i = b >> 4;
    const int r = b & 15;
    const int half = r & 1;
    const int g = r >> 1;
    const int c = half * 256 + threadIdx.x;
    double sc = 0.0, ss = 0.0;
    for (int ch = g * 16; ch < g * 16 + 16; ++ch) {
        sc += (double)pecf[(size_t)((ch * NPTS + i) * 2 + 0) * KDIR + c];
        ss += (double)pecf[(size_t)((ch * NPTS + i) * 2 + 1) * KDIR + c];
    }
    pec2[(size_t)((i * 8 + g) * 2 + 0) * KDIR + c] = sc;
    pec2[(size_t)((i * 8 + g) * 2 + 1) * KDIR + c] = ss;
}

// K6b: finish: sum 8 groups, form w_i*((R-tau)^2 + I^2)/K, block-reduce, atomic.
__global__ __launch_bounds__(256) void ecf_p2b(const double* __restrict__ pec2,
                                               float* __restrict__ out) {
    const int i = blockIdx.x >> 1;
    const int c = (blockIdx.x & 1) * 256 + threadIdx.x;
    double sc = 0.0, ss = 0.0;
    #pragma unroll
    for (int g = 0; g < 8; ++g) {
        sc += pec2[(size_t)((i * 8 + g) * 2 + 0) * KDIR + c];
        ss += pec2[(size_t)((i * 8 + g) * 2 + 1) * KDIR + c];
    }
    const double R = sc / (double)BATCH;
    const double I = ss / (double)BATCH;
    const double t = (2.0 / 17.0) * (double)(i + 1);
    const double tau = exp(-0.5 * t * t);
    const double w = (i == 0 || i == NPTS - 1) ? (1.0 / 17.0) : (2.0 / 17.0);
    const double dR = R - tau;
    double contrib = w * (dR * dR + I * I) / (double)KDIR;

    __shared__ double red[256];
    red[threadIdx.x] = contrib;
    __syncthreads();
    for (int s = 128; s > 0; s >>= 1) {
        if (threadIdx.x < s) red[threadIdx.x] += red[threadIdx.x + s];
        __syncthreads();
    }
    if (threadIdx.x == 0) atomicAdd(out, (float)red[0]);
}

// ---------------------------------------------------------------------------
extern "C" void kernel_launch(void* const* d_in, const int* in_sizes, int n_in,
                              void* d_out, int out_size, void* d_ws, size_t ws_size,
                              hipStream_t stream) {
    const float* emb = (const float*)d_in[0];   // (8192, 2048)
    const float* dir = (const float*)d_in[1];   // (2048, 512)
    float* out = (float*)d_out;

    char* ws = (char*)d_ws;
    // layout. pecf/pec2 alias the A16 region (dead after GEMM).
    _Float16* A16  = (_Float16*)(ws + 0);               // 33,554,432 B
    float*    pecf = (float*)   (ws + 0);               //  8,912,896 B (after GEMM)
    double*   pec2 = (double*)  (ws + 16777216);        //  1,114,112 B (after GEMM)
    _Float16* dT   = (_Float16*)(ws + 33554432);        //  2,097,152 B
    float*    proj = (float*)   (ws + 35651584);        // 16,777,216 B
    float*    pp   = (float*)   (ws + 52428800);        //      4,096 B
    float*    mu   = (float*)   (ws + 52432896);
    float*    isd  = (float*)   (ws + 52434944);

    hipMemsetAsync(d_out, 0, sizeof(float), stream);
    hipMemsetAsync(pp, 0, 2 * KDIR * sizeof(float), stream);

    norm_dT<<<KDIR, 256, 0, stream>>>(dir, dT);
    cvt_f16<<<(BATCH * DIM) / (256 * 8), 256, 0, stream>>>(emb, A16);
    gemm16<<<dim3(BATCH / 128, KDIR / 128), 256, 0, stream>>>(A16, dT, proj, pp);
    stats_p2<<<1, 512, 0, stream>>>(pp, mu, isd);
    ecf_p1<<<256, 256, 0, stream>>>(proj, mu, isd, pecf);
    ecf_p2a<<<272, 256, 0, stream>>>(pecf, pec2);
    ecf_p2b<<<34, 256, 0, stream>>>(pec2, out);
}